// Round 1
// baseline (2595.684 us; speedup 1.0000x reference)
//
#include <hip/hip_runtime.h>
#include <hip/hip_bf16.h>

// Problem constants
#define B_    2
#define S_    2048
#define DIM_  512
#define H_    8
#define HD_   64
#define TOUT_ 1536   // 2*QK + DIM

// ---------- dtype helpers ----------
__device__ __forceinline__ float bf2f(unsigned int u) { return __uint_as_float(u << 16); }

__device__ __forceinline__ float4 ldf4(const float* p) { return *reinterpret_cast<const float4*>(p); }
__device__ __forceinline__ float4 ldf4(const __hip_bfloat16* p) {
    uint2 u = *reinterpret_cast<const uint2*>(p);
    float4 r;
    r.x = bf2f(u.x & 0xffffu);
    r.y = bf2f(u.x >> 16);
    r.z = bf2f(u.y & 0xffffu);
    r.w = bf2f(u.y >> 16);
    return r;
}
__device__ __forceinline__ float ldf1(const float* p) { return *p; }
__device__ __forceinline__ float ldf1(const __hip_bfloat16* p) {
    return bf2f((unsigned int)*reinterpret_cast<const unsigned short*>(p));
}
__device__ __forceinline__ void stf1(float* p, float v) { *p = v; }
__device__ __forceinline__ void stf1(__hip_bfloat16* p, float v) { *p = __float2bfloat16(v); }

// ---------- dtype detection ----------
// flags[0]: 0 = float tensors are fp32, 1 = bf16
// flags[1]: mask class: 0=u8 bool, 1=int32, 2=bf16, 3=fp32
__global__ void tmha_detect(const unsigned char* xb, const unsigned char* mb, int* flags) {
    __shared__ int s_exp, s_bf, s_f, s_u8;
    int tid = threadIdx.x;
    if (tid == 0) { s_exp = 0; s_bf = 0; s_f = 0; s_u8 = 0; }
    __syncthreads();
    int cexp = 0, cbf = 0, cf = 0, cu8 = 0;
    // x ~ N(0,1): if bf16, byte at pos 4i+1 is a high (sign+exp) byte -> concentrated range;
    // if fp32, it's a mantissa byte -> ~uniform (~28% hit rate on the range test).
    for (int i = tid; i < 1024; i += 256) {
        unsigned char v = xb[4 * i + 1];
        if ((v >= 0x20 && v <= 0x43) || (v >= 0xA0 && v <= 0xC3)) cexp++;
    }
    // mask byte-pattern classification over first 4096 bytes
    for (int i = tid; i < 4096; i += 256) {
        unsigned char v = mb[i];
        if (v == 0x3F || v == 0x80) {          // float-ish payload bytes (1.0f / 1.0bf16)
            cf++;
            if ((i & 3) == 1) cbf++;           // bf16 puts 0x3F at pos≡1 mod 4; fp32 never does
        } else if (v != 0 && (i & 3) != 0) {
            cu8++;                             // int32 only has nonzero at pos≡0 mod 4
        }
    }
    atomicAdd(&s_exp, cexp); atomicAdd(&s_bf, cbf);
    atomicAdd(&s_f, cf);     atomicAdd(&s_u8, cu8);
    __syncthreads();
    if (tid == 0) {
        flags[0] = (s_exp > 640) ? 1 : 0;
        int mcls;
        if (s_bf > 0)      mcls = 2;
        else if (s_f > 0)  mcls = 3;
        else if (s_u8 > 0) mcls = 0;
        else               mcls = 1;
        flags[1] = mcls;
    }
}

__global__ void tmha_decode_mask(const unsigned char* mb, const int* flags, int* wm) {
    int i = blockIdx.x * 256 + threadIdx.x;
    if (i >= B_ * S_) return;
    int cls = flags[1];
    int v;
    if (cls == 0)      v = (mb[i] != 0);
    else if (cls == 1) v = (reinterpret_cast<const int*>(mb)[i] != 0);
    else if (cls == 2) v = ((reinterpret_cast<const unsigned short*>(mb)[i] & 0x7fffu) != 0);
    else               v = ((reinterpret_cast<const unsigned int*>(mb)[i] & 0x7fffffffu) != 0);
    wm[i] = v;
}

// ---------- t = x @ W_trans^T  -> fp32 in ws ----------
template <typename T>
__global__ __launch_bounds__(256) void tmha_gemm1(const T* __restrict__ x,
                                                  const T* __restrict__ W,
                                                  float* __restrict__ t,
                                                  const int* __restrict__ flags, int tag) {
    if (flags[0] != tag) return;
    __shared__ float xs[DIM_];
    int bid = blockIdx.x;
    int row = bid / 6;            // b*S + s
    int seg = bid % 6;
    int o = seg * 256 + threadIdx.x;
    const T* xrow = x + (size_t)row * DIM_;
    for (int e = threadIdx.x; e < DIM_; e += 256) xs[e] = ldf1(xrow + e);
    __syncthreads();
    const T* wr = W + (size_t)o * DIM_;
    float acc = 0.f;
    for (int d = 0; d < DIM_; d += 4) {
        float4 wv = ldf4(wr + d);
        acc += xs[d] * wv.x + xs[d + 1] * wv.y + xs[d + 2] * wv.z + xs[d + 3] * wv.w;
    }
    t[(size_t)row * TOUT_ + o] = acc;
}

// ---------- rotate q,k where mask ----------
template <typename T>
__global__ __launch_bounds__(256) void tmha_rot(const T* __restrict__ rot,
                                                const int* __restrict__ wm,
                                                float* __restrict__ t,
                                                const int* __restrict__ flags, int tag) {
    if (flags[0] != tag) return;
    int row = blockIdx.x;                 // b*S + s
    if (!wm[row]) return;
    __shared__ float rotT[64 * 65];       // rotT[j*65+i] = rot[i][j]
    __shared__ float qk[1024];
    const T* rp = rot + (size_t)row * 4096;
    for (int e = threadIdx.x * 4; e < 4096; e += 1024) {
        float4 v = ldf4(rp + e);
        int i = e >> 6, j = e & 63;
        rotT[(j + 0) * 65 + i] = v.x;
        rotT[(j + 1) * 65 + i] = v.y;
        rotT[(j + 2) * 65 + i] = v.z;
        rotT[(j + 3) * 65 + i] = v.w;
    }
    float* trow = t + (size_t)row * TOUT_;
    for (int e = threadIdx.x; e < 1024; e += 256) qk[e] = trow[e];
    __syncthreads();
    float res[4];
    for (int r = 0; r < 4; r++) {
        int u = threadIdx.x + 256 * r;    // [sel(1)|h(3)|i(6)]
        int i = u & 63;
        int base = u & ~63;               // sel*512 + h*64
        float acc = 0.f;
        for (int j = 0; j < 64; j++) acc += rotT[j * 65 + i] * qk[base + j];
        res[r] = acc;
    }
    __syncthreads();
    for (int r = 0; r < 4; r++) {
        int u = threadIdx.x + 256 * r;
        trow[u] = res[r];
    }
}

// ---------- taylor attention (flash-style, fp32) ----------
// grid: B * H * (S/16) blocks; 256 threads = 4 waves, each wave owns 4 q rows.
__global__ __launch_bounds__(256) void tmha_attn(const float* __restrict__ t,
                                                 const int* __restrict__ wm,
                                                 float* __restrict__ attn) {
    __shared__ float Kt[64 * 65];         // Kt[d*65+kk]
    __shared__ float Vt[64 * 64];         // Vt[kk*64+d]
    __shared__ float qs[16 * 64];
    __shared__ float wbuf[16 * 64];
    int tid = threadIdx.x;
    int lane = tid & 63;
    int w = tid >> 6;
    int bid = blockIdx.x;
    int b = bid >> 10;                    // H*(S/16) = 1024 blocks per batch
    int rem = bid & 1023;
    int h = rem >> 7;
    int qt = rem & 127;
    int rowb = b * S_;

    // load this wave's 4 q rows into LDS (lane = dim)
    for (int r = 0; r < 4; r++) {
        int qrow = qt * 16 + w * 4 + r;
        qs[(w * 4 + r) * 64 + lane] = t[(size_t)(rowb + qrow) * TOUT_ + h * 64 + lane];
    }

    float outacc[4] = {0.f, 0.f, 0.f, 0.f};
    float dacc[4]   = {0.f, 0.f, 0.f, 0.f};

    for (int kt2 = 0; kt2 < S_; kt2 += 64) {
        __syncthreads();
        // stage K (transposed, padded) and V (natural) tiles
        for (int e4 = tid; e4 < 1024; e4 += 256) {
            int kk = e4 >> 4;
            int d4 = (e4 & 15) * 4;
            const float* kbase = &t[(size_t)(rowb + kt2 + kk) * TOUT_ + 512 + h * 64 + d4];
            const float* vbase = &t[(size_t)(rowb + kt2 + kk) * TOUT_ + 1024 + h * 64 + d4];
            float4 kv = *reinterpret_cast<const float4*>(kbase);
            float4 vv = *reinterpret_cast<const float4*>(vbase);
            Kt[(d4 + 0) * 65 + kk] = kv.x;
            Kt[(d4 + 1) * 65 + kk] = kv.y;
            Kt[(d4 + 2) * 65 + kk] = kv.z;
            Kt[(d4 + 3) * 65 + kk] = kv.w;
            *reinterpret_cast<float4*>(&Vt[kk * 64 + d4]) = vv;
        }
        __syncthreads();

        // phase 1: lane = key; compute taylor weights for 4 q rows
        int key = kt2 + lane;
        int m = wm[b * S_ + key];
        float s0 = 0.f, s1 = 0.f, s2 = 0.f, s3 = 0.f;
        for (int d = 0; d < 64; d++) {
            float kv = Kt[d * 65 + lane];
            s0 += qs[(w * 4 + 0) * 64 + d] * kv;
            s1 += qs[(w * 4 + 1) * 64 + d] * kv;
            s2 += qs[(w * 4 + 2) * 64 + d] * kv;
            s3 += qs[(w * 4 + 3) * 64 + d] * kv;
        }
        float sc[4] = {s0, s1, s2, s3};
        for (int r = 0; r < 4; r++) {
            float s = sc[r] * 0.125f;
            float wg = 1.0f + s + 0.5f * s * s;
            wg = m ? wg : 0.0f;
            wbuf[(w * 4 + r) * 64 + lane] = wg;
            dacc[r] += wg;
        }
        // phase 2: lane = dim; accumulate weighted V
        for (int k = 0; k < 64; k++) {
            float vv = Vt[k * 64 + lane];
            outacc[0] += wbuf[(w * 4 + 0) * 64 + k] * vv;
            outacc[1] += wbuf[(w * 4 + 1) * 64 + k] * vv;
            outacc[2] += wbuf[(w * 4 + 2) * 64 + k] * vv;
            outacc[3] += wbuf[(w * 4 + 3) * 64 + k] * vv;
        }
    }

    // wave-reduce denominators and write out
    for (int r = 0; r < 4; r++) {
        float d = dacc[r];
        for (int off = 32; off > 0; off >>= 1) d += __shfl_down(d, off, 64);
        d = __shfl(d, 0, 64);
        int qrow = qt * 16 + w * 4 + r;
        attn[(size_t)(rowb + qrow) * DIM_ + h * 64 + lane] = outacc[r] / d;
    }
}

// ---------- out = attn @ W_o^T ----------
template <typename T>
__global__ __launch_bounds__(256) void tmha_gemm2(const float* __restrict__ attn,
                                                  const T* __restrict__ Wo,
                                                  T* __restrict__ out,
                                                  const int* __restrict__ flags, int tag) {
    if (flags[0] != tag) return;
    __shared__ float arow[DIM_];
    int row = blockIdx.x >> 1;            // b*S + s
    int seg = blockIdx.x & 1;
    int dcol = seg * 256 + threadIdx.x;
    for (int e = threadIdx.x; e < DIM_; e += 256) arow[e] = attn[(size_t)row * DIM_ + e];
    __syncthreads();
    const T* wr = Wo + (size_t)dcol * DIM_;
    float acc = 0.f;
    for (int e = 0; e < DIM_; e += 4) {
        float4 wv = ldf4(wr + e);
        acc += arow[e] * wv.x + arow[e + 1] * wv.y + arow[e + 2] * wv.z + arow[e + 3] * wv.w;
    }
    stf1(out + (size_t)row * DIM_ + dcol, acc);
}

extern "C" void kernel_launch(void* const* d_in, const int* in_sizes, int n_in,
                              void* d_out, int out_size, void* d_ws, size_t ws_size,
                              hipStream_t stream) {
    (void)in_sizes; (void)n_in; (void)out_size; (void)ws_size;
    const void* x    = d_in[0];
    const void* mask = d_in[1];
    const void* rot  = d_in[2];
    const void* Wt   = d_in[3];
    const void* Wo   = d_in[4];

    char* ws = (char*)d_ws;
    int* flags  = (int*)ws;                                   // 64 B
    int* wmask  = (int*)(ws + 64);                            // 4096 * 4 B
    float* t    = (float*)(ws + 64 + 16384);                  // B*S*1536 fp32 = 25,165,824 B
    float* attn = (float*)(ws + 64 + 16384 + 25165824);       // B*S*512 fp32 = 8,388,608 B

    tmha_detect<<<1, 256, 0, stream>>>((const unsigned char*)x, (const unsigned char*)mask, flags);
    tmha_decode_mask<<<16, 256, 0, stream>>>((const unsigned char*)mask, flags, wmask);

    // gemm1: B*S rows, 6 segments of 256 outputs
    tmha_gemm1<__hip_bfloat16><<<B_ * S_ * 6, 256, 0, stream>>>(
        (const __hip_bfloat16*)x, (const __hip_bfloat16*)Wt, t, flags, 1);
    tmha_gemm1<float><<<B_ * S_ * 6, 256, 0, stream>>>(
        (const float*)x, (const float*)Wt, t, flags, 0);

    tmha_rot<__hip_bfloat16><<<B_ * S_, 256, 0, stream>>>(
        (const __hip_bfloat16*)rot, wmask, t, flags, 1);
    tmha_rot<float><<<B_ * S_, 256, 0, stream>>>(
        (const float*)rot, wmask, t, flags, 0);

    tmha_attn<<<B_ * H_ * (S_ / 16), 256, 0, stream>>>(t, wmask, attn);

    tmha_gemm2<__hip_bfloat16><<<B_ * S_ * 2, 256, 0, stream>>>(
        attn, (const __hip_bfloat16*)Wo, (__hip_bfloat16*)d_out, flags, 1);
    tmha_gemm2<float><<<B_ * S_ * 2, 256, 0, stream>>>(
        attn, (const float*)Wo, (float*)d_out, flags, 0);
}